// Round 13
// baseline (224.261 us; speedup 1.0000x reference)
//
#include <hip/hip_runtime.h>
#include <hip/hip_bf16.h>

// DeeperGCN round-12: pair-interleaved aggregation. R11 showed the agg loop is
// latency-exposed per node (one dependent chain per wave). Now each wave owns a
// node PAIR (p, p+25000): joint 16+16 chunks (16 gathers in flight per half-wave,
// 2x R11), 8+8 joint, solo finish. rowdeg packed int2; self read from bf16
// (agg2 no longer touches fp32 X1 -> L2-hot path).
// 7 dispatches: detect -> bucket+enc -> sort -> agg -> mlp -> agg -> mlpfin.

#define NN 50000
#define EE 800000
#define FIN 128
#define HD 64
#define NBUCK 196       // dst>>8: 196*256 = 50176 >= NN
#define CAP 4608        // bucket capacity: mean 4082 + 8 sigma (validated R8/R10)
#define EPB 2048        // edges per bucket-build block
#define NBLK 391        // 391*2048 = 800768 >= EE

typedef unsigned short u16;
typedef unsigned int u32;
using bf16x8 = __attribute__((ext_vector_type(8))) short;
using f32x4 = __attribute__((ext_vector_type(4))) float;

__device__ __forceinline__ float bf2f(u16 u) {
    u32 x = ((u32)u) << 16;
    float f;
    __builtin_memcpy(&f, &x, 4);
    return f;
}
__device__ __forceinline__ short f2bf(float f) {
    u32 u;
    __builtin_memcpy(&u, &f, 4);
    u32 r = (u + 0x7fffu + ((u >> 16) & 1u)) >> 16;  // RNE
    return (short)r;
}

// ---------------- detect (1 block): layout flag + zero bcnt ----------------
__global__ __launch_bounds__(256) void k_detect(const int* __restrict__ ei,
                                                int* __restrict__ flag,
                                                int* __restrict__ bcnt) {
    __shared__ int red[256];
    int t = threadIdx.x;
    int any = 0;
#pragma unroll
    for (int k = 0; k < 4; k++) any |= (ei[2 * (t * 4 + k) + 1] != 0) ? 1 : 0;
    red[t] = any;
    __syncthreads();
    for (int d = 128; d >= 1; d >>= 1) {
        if (t < d) red[t] |= red[t + d];
        __syncthreads();
    }
    if (t == 0) *flag = red[0];  // 1 => int32 layout
    if (t < NBUCK) bcnt[t] = 0;
}

// ---------------- merged bucket-build + encoder ----------------
__global__ __launch_bounds__(256) void k_bucket_enc(
    const int* __restrict__ ei, const int* __restrict__ flag, int* __restrict__ bcnt,
    u32* __restrict__ barr, const float* __restrict__ x, const float* __restrict__ W,
    const float* __restrict__ b, u16* __restrict__ Abf) {
    __shared__ short wtE[64 * 136];
    int tid = threadIdx.x;
    if (blockIdx.x < NBLK) {
        __shared__ int hist[NBUCK];
        __shared__ int gbase[NBUCK];
        __shared__ int cur[NBUCK];
        for (int i = tid; i < NBUCK; i += 256) { hist[i] = 0; cur[i] = 0; }
        __syncthreads();
        int is32 = *flag;
        int e0 = blockIdx.x * EPB;
        u32 pk[8];
#pragma unroll
        for (int j = 0; j < 8; j++) {
            int e = e0 + j * 256 + tid;
            if (e < EE) {
                int s, d;
                if (is32) {
                    s = ei[e];
                    d = ei[EE + e];
                } else {
                    int2 sp = ((const int2*)ei)[e];
                    int2 dp = ((const int2*)ei)[EE + e];
                    s = sp.x;
                    d = dp.x;
                }
                pk[j] = (u32)s | ((u32)(d & 255) << 16) | ((u32)(d >> 8) << 24);
                atomicAdd(&hist[d >> 8], 1);
            } else {
                pk[j] = 0xFFFFFFFFu;
            }
        }
        __syncthreads();
        for (int i = tid; i < NBUCK; i += 256)
            if (hist[i] > 0) gbase[i] = atomicAdd(&bcnt[i], hist[i]);
        __syncthreads();
#pragma unroll
        for (int j = 0; j < 8; j++) {
            if (pk[j] != 0xFFFFFFFFu) {
                int bk = pk[j] >> 24;
                int pos = gbase[bk] + atomicAdd(&cur[bk], 1);
                if (pos < CAP) barr[(size_t)bk * CAP + pos] = pk[j] & 0x00FFFFFFu;
            }
        }
        return;
    }
    // encoder: Abf[n,0:64] = bf16(x[n,0:128] @ W + b)
    for (int i = tid; i < FIN * HD; i += 256) wtE[(i & 63) * 136 + (i >> 6)] = f2bf(W[i]);
    __syncthreads();

    int lane = tid & 63, wid = tid >> 6;
    int l16 = lane & 15, q = lane >> 4;
    int m0 = (int)(blockIdx.x - NBLK) * 64 + wid * 16;
    int mrow = m0 + l16;
    if (mrow >= NN) mrow = NN - 1;

    bf16x8 af[4];
#pragma unroll
    for (int c = 0; c < 4; c++) {
        const float4* p = (const float4*)(x + (size_t)mrow * FIN + c * 32 + q * 8);
        float4 p0 = p[0], p1 = p[1];
        af[c][0] = f2bf(p0.x); af[c][1] = f2bf(p0.y); af[c][2] = f2bf(p0.z); af[c][3] = f2bf(p0.w);
        af[c][4] = f2bf(p1.x); af[c][5] = f2bf(p1.y); af[c][6] = f2bf(p1.z); af[c][7] = f2bf(p1.w);
    }
    f32x4 acc[4];
#pragma unroll
    for (int u = 0; u < 4; u++) {
        f32x4 z = {0.f, 0.f, 0.f, 0.f};
#pragma unroll
        for (int c = 0; c < 4; c++) {
            bf16x8 wf = *(const bf16x8*)(const void*)&wtE[(u * 16 + l16) * 136 + c * 32 + q * 8];
            z = __builtin_amdgcn_mfma_f32_16x16x32_bf16(af[c], wf, z, 0, 0, 0);
        }
        acc[u] = z;
    }
#pragma unroll
    for (int u = 0; u < 4; u++) {
        int col = u * 16 + l16;
        float bc = b[col];
#pragma unroll
        for (int r = 0; r < 4; r++) {
            int node = m0 + q * 4 + r;
            if (node < NN) Abf[(size_t)node * HD + col] = (u16)f2bf(acc[u][r] + bc);
        }
    }
}

// ---------------- per-bucket sort: bucket -> sorted CSR runs (dense writes) -------
__global__ __launch_bounds__(256) void k_sort(const int* __restrict__ bcnt,
                                              const u32* __restrict__ barr,
                                              u16* __restrict__ eSrc,
                                              int2* __restrict__ rowdeg) {
    __shared__ u32 pkL[CAP];
    __shared__ u16 outL[CAP];
    __shared__ int hist[256];
    __shared__ int excl[256];
    __shared__ int cur[256];
    int bk = blockIdx.x;
    int t = threadIdx.x;
    int cnt = bcnt[bk];
    if (cnt > CAP) cnt = CAP;
    const u32* bp = barr + (size_t)bk * CAP;
    for (int i = t; i < cnt; i += 256) pkL[i] = bp[i];
    hist[t] = 0;
    __syncthreads();
    for (int i = t; i < cnt; i += 256) atomicAdd(&hist[(pkL[i] >> 16) & 0xFF], 1);
    __syncthreads();
    int v = hist[t];
    excl[t] = v;
    __syncthreads();
#pragma unroll
    for (int d = 1; d < 256; d <<= 1) {
        int u = (t >= d) ? excl[t - d] : 0;
        __syncthreads();
        excl[t] += u;
        __syncthreads();
    }
    int ex = excl[t] - v;
    cur[t] = ex;
    int node = bk * 256 + t;
    if (node < NN) rowdeg[node] = make_int2(bk * CAP + ex, v);
    __syncthreads();
    for (int i = t; i < cnt; i += 256) {
        u32 pk = pkL[i];
        int pos = atomicAdd(&cur[(pk >> 16) & 0xFF], 1);
        outL[pos] = (u16)pk;
    }
    __syncthreads();
    int cnt2 = (cnt + 1) >> 1;
    u32* dst = (u32*)(void*)(eSrc + (size_t)bk * CAP);
    const u32* src = (const u32*)(const void*)outL;
    for (int i = t; i < cnt2; i += 256) dst[i] = src[i];
}

// ---------------- softmax aggregation: node-PAIR interleaved streams ----------------
// Wave owns nodes (p, p+25000): joint 16+16 chunks (16 gathers in flight per
// half-wave), joint 8+8, then solo 16/8/pair/single finish per node.
__global__ __launch_bounds__(256) void k_agg(const u16* __restrict__ Xbf,
                                             const int2* __restrict__ rowdeg,
                                             const u16* __restrict__ eSrc,
                                             const float* __restrict__ tptr,
                                             u16* __restrict__ OUTbf) {
    int t = threadIdx.x;
    int lane = t & 63, wid = t >> 6;
    int half = lane >> 5, cp = lane & 31;
    float tt = tptr[0];
    const int HALF = NN / 2;

    auto edge = [tt](u32 u, float& n0_, float& d0_, float& n1_, float& d1_) {
        float m0 = fmaxf(bf2f((u16)u), 0.f) + 1e-7f;
        float m1 = fmaxf(bf2f((u16)(u >> 16)), 0.f) + 1e-7f;
        float p0 = __expf(m0 * tt);
        float p1 = __expf(m1 * tt);
        d0_ += p0; n0_ += m0 * p0;
        d1_ += p1; n1_ += m1 * p1;
    };

    for (int p = blockIdx.x * 4 + wid; p < HALF; p += gridDim.x * 4) {
        int n0 = p, n1 = p + HALF;
        int2 rd0 = rowdeg[n0], rd1 = rowdeg[n1];
        int b0 = rd0.x, e0 = rd0.x + rd0.y;
        int b1 = rd1.x, e1 = rd1.x + rd1.y;
        u32 su0 = *(const u32*)(const void*)(Xbf + (size_t)n0 * HD + 2 * cp);
        u32 su1 = *(const u32*)(const void*)(Xbf + (size_t)n1 * HD + 2 * cp);
        float nA0 = 0, dA0 = 0, nA1 = 0, dA1 = 0;
        float nB0 = 0, dB0 = 0, nB1 = 0, dB1 = 0;

        // joint 16+16: two independent 8-deep gather streams per half-wave
        while (b0 + 16 <= e0 && b1 + 16 <= e1) {
            int sv[16];
#pragma unroll
            for (int k = 0; k < 8; k++) sv[k] = eSrc[b0 + 2 * k + half];
#pragma unroll
            for (int k = 0; k < 8; k++) sv[8 + k] = eSrc[b1 + 2 * k + half];
            u32 uu[16];
#pragma unroll
            for (int k = 0; k < 16; k++)
                uu[k] = *(const u32*)(const void*)(Xbf + (size_t)sv[k] * HD + 2 * cp);
#pragma unroll
            for (int k = 0; k < 8; k++) edge(uu[k], nA0, dA0, nA1, dA1);
#pragma unroll
            for (int k = 0; k < 8; k++) edge(uu[8 + k], nB0, dB0, nB1, dB1);
            b0 += 16; b1 += 16;
        }
        // joint 8+8
        while (b0 + 8 <= e0 && b1 + 8 <= e1) {
            int sv[8];
#pragma unroll
            for (int k = 0; k < 4; k++) sv[k] = eSrc[b0 + 2 * k + half];
#pragma unroll
            for (int k = 0; k < 4; k++) sv[4 + k] = eSrc[b1 + 2 * k + half];
            u32 uu[8];
#pragma unroll
            for (int k = 0; k < 8; k++)
                uu[k] = *(const u32*)(const void*)(Xbf + (size_t)sv[k] * HD + 2 * cp);
#pragma unroll
            for (int k = 0; k < 4; k++) edge(uu[k], nA0, dA0, nA1, dA1);
#pragma unroll
            for (int k = 0; k < 4; k++) edge(uu[4 + k], nB0, dB0, nB1, dB1);
            b0 += 8; b1 += 8;
        }

        auto finish = [&](int base, int end, float& N0, float& D0, float& N1, float& D1) {
            for (; base + 16 <= end; base += 16) {
                int sv[8];
#pragma unroll
                for (int k = 0; k < 8; k++) sv[k] = eSrc[base + 2 * k + half];
                u32 uu[8];
#pragma unroll
                for (int k = 0; k < 8; k++)
                    uu[k] = *(const u32*)(const void*)(Xbf + (size_t)sv[k] * HD + 2 * cp);
#pragma unroll
                for (int k = 0; k < 8; k++) edge(uu[k], N0, D0, N1, D1);
            }
            if (base + 8 <= end) {
                int sv[4];
#pragma unroll
                for (int k = 0; k < 4; k++) sv[k] = eSrc[base + 2 * k + half];
                u32 uu[4];
#pragma unroll
                for (int k = 0; k < 4; k++)
                    uu[k] = *(const u32*)(const void*)(Xbf + (size_t)sv[k] * HD + 2 * cp);
#pragma unroll
                for (int k = 0; k < 4; k++) edge(uu[k], N0, D0, N1, D1);
                base += 8;
            }
            int i = base + half;
            for (; i + 2 < end; i += 4) {
                int sva = eSrc[i], svb = eSrc[i + 2];
                u32 ua = *(const u32*)(const void*)(Xbf + (size_t)sva * HD + 2 * cp);
                u32 ub = *(const u32*)(const void*)(Xbf + (size_t)svb * HD + 2 * cp);
                edge(ua, N0, D0, N1, D1);
                edge(ub, N0, D0, N1, D1);
            }
            if (i < end) {
                u32 u = *(const u32*)(const void*)(Xbf + (size_t)eSrc[i] * HD + 2 * cp);
                edge(u, N0, D0, N1, D1);
            }
        };
        finish(b0, e0, nA0, dA0, nA1, dA1);
        finish(b1, e1, nB0, dB0, nB1, dB1);

        nA0 += __shfl_xor(nA0, 32, 64); dA0 += __shfl_xor(dA0, 32, 64);
        nA1 += __shfl_xor(nA1, 32, 64); dA1 += __shfl_xor(dA1, 32, 64);
        nB0 += __shfl_xor(nB0, 32, 64); dB0 += __shfl_xor(dB0, 32, 64);
        nB1 += __shfl_xor(nB1, 32, 64); dB1 += __shfl_xor(dB1, 32, 64);
        if (half == 0) {
            float a0 = nA0 / (dA0 + 1e-16f) + bf2f((u16)su0);
            float a1 = nA1 / (dA1 + 1e-16f) + bf2f((u16)(su0 >> 16));
            *(u32*)(void*)(OUTbf + (size_t)n0 * HD + 2 * cp) =
                (u32)(u16)f2bf(a0) | ((u32)(u16)f2bf(a1) << 16);
            float c0 = nB0 / (dB0 + 1e-16f) + bf2f((u16)su1);
            float c1 = nB1 / (dB1 + 1e-16f) + bf2f((u16)(su1 >> 16));
            *(u32*)(void*)(OUTbf + (size_t)n1 * HD + 2 * cp) =
                (u32)(u16)f2bf(c0) | ((u32)(u16)f2bf(c1) << 16);
        }
    }
}

// ---------------- conv1 MLP (MFMA): relu(LN(in@W1+b1))@W2+b2 -> X1 fp32 + bf16 ----------------
__global__ __launch_bounds__(256) void k_mlp(const u16* __restrict__ INbf,
                                             const float* __restrict__ W1,
                                             const float* __restrict__ B1,
                                             const float* __restrict__ G1,
                                             const float* __restrict__ BE1,
                                             const float* __restrict__ W2,
                                             const float* __restrict__ B2,
                                             float* __restrict__ OUTfp,
                                             u16* __restrict__ OUTbf) {
    __shared__ short wt1[128 * 72];
    __shared__ short wt2[64 * 136];
    __shared__ short hbuf[64 * 136];
    int tid = threadIdx.x;
    for (int i = tid; i < HD * 128; i += 256) wt1[(i & 127) * 72 + (i >> 7)] = f2bf(W1[i]);
    for (int i = tid; i < 128 * HD; i += 256) wt2[(i & 63) * 136 + (i >> 6)] = f2bf(W2[i]);
    __syncthreads();

    int lane = tid & 63, wid = tid >> 6;
    int l16 = lane & 15, q = lane >> 4;
    int m0 = blockIdx.x * 64 + wid * 16;
    int mrow = m0 + l16;
    if (mrow >= NN) mrow = NN - 1;

    float b1v[8], g1v[8], bev[8];
#pragma unroll
    for (int tl = 0; tl < 8; tl++) {
        int j = tl * 16 + l16;
        b1v[tl] = B1[j]; g1v[tl] = G1[j]; bev[tl] = BE1[j];
    }

    bf16x8 a0 = *(const bf16x8*)(const void*)(INbf + (size_t)mrow * HD + q * 8);
    bf16x8 a1 = *(const bf16x8*)(const void*)(INbf + (size_t)mrow * HD + 32 + q * 8);
    f32x4 acc1[8];
#pragma unroll
    for (int tl = 0; tl < 8; tl++) {
        bf16x8 w0 = *(const bf16x8*)(const void*)&wt1[(tl * 16 + l16) * 72 + q * 8];
        bf16x8 w1 = *(const bf16x8*)(const void*)&wt1[(tl * 16 + l16) * 72 + 32 + q * 8];
        f32x4 z = {0.f, 0.f, 0.f, 0.f};
        z = __builtin_amdgcn_mfma_f32_16x16x32_bf16(a0, w0, z, 0, 0, 0);
        z = __builtin_amdgcn_mfma_f32_16x16x32_bf16(a1, w1, z, 0, 0, 0);
        acc1[tl] = z;
    }
    float S[4] = {0, 0, 0, 0}, Q[4] = {0, 0, 0, 0};
#pragma unroll
    for (int tl = 0; tl < 8; tl++)
#pragma unroll
        for (int r = 0; r < 4; r++) {
            float v = acc1[tl][r] + b1v[tl];
            acc1[tl][r] = v;
            S[r] += v; Q[r] += v * v;
        }
#pragma unroll
    for (int m = 8; m >= 1; m >>= 1)
#pragma unroll
        for (int r = 0; r < 4; r++) {
            S[r] += __shfl_xor(S[r], m, 64);
            Q[r] += __shfl_xor(Q[r], m, 64);
        }
    float mu[4], rs[4];
#pragma unroll
    for (int r = 0; r < 4; r++) {
        mu[r] = S[r] * (1.f / 128.f);
        float var = Q[r] * (1.f / 128.f) - mu[r] * mu[r];
        rs[r] = rsqrtf(var + 1e-5f);
    }
#pragma unroll
    for (int tl = 0; tl < 8; tl++)
#pragma unroll
        for (int r = 0; r < 4; r++) {
            float h = fmaxf((acc1[tl][r] - mu[r]) * rs[r] * g1v[tl] + bev[tl], 0.f);
            hbuf[(wid * 16 + q * 4 + r) * 136 + tl * 16 + l16] = f2bf(h);
        }
    // wave-private LDS rows; per-wave DS ordering suffices

    bf16x8 a2[4];
#pragma unroll
    for (int c = 0; c < 4; c++)
        a2[c] = *(const bf16x8*)(const void*)&hbuf[(wid * 16 + l16) * 136 + c * 32 + q * 8];
    f32x4 acc2[4];
#pragma unroll
    for (int u = 0; u < 4; u++) {
        f32x4 z = {0.f, 0.f, 0.f, 0.f};
#pragma unroll
        for (int c = 0; c < 4; c++) {
            bf16x8 wf = *(const bf16x8*)(const void*)&wt2[(u * 16 + l16) * 136 + c * 32 + q * 8];
            z = __builtin_amdgcn_mfma_f32_16x16x32_bf16(a2[c], wf, z, 0, 0, 0);
        }
        acc2[u] = z;
    }
#pragma unroll
    for (int u = 0; u < 4; u++) {
        int col = u * 16 + l16;
        float bc = B2[col];
#pragma unroll
        for (int r = 0; r < 4; r++) {
            int node = m0 + q * 4 + r;
            if (node < NN) {
                float val = acc2[u][r] + bc;
                OUTfp[(size_t)node * HD + col] = val;
                OUTbf[(size_t)node * HD + col] = (u16)f2bf(val);
            }
        }
    }
}

// ---------------- conv2 MLP + fused tail ----------------
__global__ __launch_bounds__(256) void k_mlpfin(const u16* __restrict__ INbf,
                                                const float* __restrict__ W1,
                                                const float* __restrict__ B1,
                                                const float* __restrict__ G1,
                                                const float* __restrict__ BE1,
                                                const float* __restrict__ W2,
                                                const float* __restrict__ B2,
                                                const float* __restrict__ X1,
                                                const float* __restrict__ LG,
                                                const float* __restrict__ LB,
                                                const float* __restrict__ NG,
                                                const float* __restrict__ NBv,
                                                const float* __restrict__ LW,
                                                const float* __restrict__ LBias,
                                                float* __restrict__ out) {
    __shared__ short wt1[128 * 72];
    __shared__ short wt2[64 * 136];
    __shared__ short hbuf[64 * 136];
    int tid = threadIdx.x;
    for (int i = tid; i < HD * 128; i += 256) wt1[(i & 127) * 72 + (i >> 7)] = f2bf(W1[i]);
    for (int i = tid; i < 128 * HD; i += 256) wt2[(i & 63) * 136 + (i >> 6)] = f2bf(W2[i]);
    __syncthreads();

    int lane = tid & 63, wid = tid >> 6;
    int l16 = lane & 15, q = lane >> 4;
    int m0 = blockIdx.x * 64 + wid * 16;
    int mrow = m0 + l16;
    if (mrow >= NN) mrow = NN - 1;

    float b1v[8], g1v[8], bev[8];
#pragma unroll
    for (int tl = 0; tl < 8; tl++) {
        int j = tl * 16 + l16;
        b1v[tl] = B1[j]; g1v[tl] = G1[j]; bev[tl] = BE1[j];
    }

    bf16x8 a0 = *(const bf16x8*)(const void*)(INbf + (size_t)mrow * HD + q * 8);
    bf16x8 a1 = *(const bf16x8*)(const void*)(INbf + (size_t)mrow * HD + 32 + q * 8);
    f32x4 acc1[8];
#pragma unroll
    for (int tl = 0; tl < 8; tl++) {
        bf16x8 w0 = *(const bf16x8*)(const void*)&wt1[(tl * 16 + l16) * 72 + q * 8];
        bf16x8 w1 = *(const bf16x8*)(const void*)&wt1[(tl * 16 + l16) * 72 + 32 + q * 8];
        f32x4 z = {0.f, 0.f, 0.f, 0.f};
        z = __builtin_amdgcn_mfma_f32_16x16x32_bf16(a0, w0, z, 0, 0, 0);
        z = __builtin_amdgcn_mfma_f32_16x16x32_bf16(a1, w1, z, 0, 0, 0);
        acc1[tl] = z;
    }
    float S[4] = {0, 0, 0, 0}, Q[4] = {0, 0, 0, 0};
#pragma unroll
    for (int tl = 0; tl < 8; tl++)
#pragma unroll
        for (int r = 0; r < 4; r++) {
            float v = acc1[tl][r] + b1v[tl];
            acc1[tl][r] = v;
            S[r] += v; Q[r] += v * v;
        }
#pragma unroll
    for (int m = 8; m >= 1; m >>= 1)
#pragma unroll
        for (int r = 0; r < 4; r++) {
            S[r] += __shfl_xor(S[r], m, 64);
            Q[r] += __shfl_xor(Q[r], m, 64);
        }
#pragma unroll
    for (int r = 0; r < 4; r++) {
        float mu = S[r] * (1.f / 128.f);
        float var = Q[r] * (1.f / 128.f) - mu * mu;
        float rs = rsqrtf(var + 1e-5f);
        S[r] = mu; Q[r] = rs;  // reuse
    }
#pragma unroll
    for (int tl = 0; tl < 8; tl++)
#pragma unroll
        for (int r = 0; r < 4; r++) {
            float h = fmaxf((acc1[tl][r] - S[r]) * Q[r] * g1v[tl] + bev[tl], 0.f);
            hbuf[(wid * 16 + q * 4 + r) * 136 + tl * 16 + l16] = f2bf(h);
        }

    bf16x8 a2[4];
#pragma unroll
    for (int c = 0; c < 4; c++)
        a2[c] = *(const bf16x8*)(const void*)&hbuf[(wid * 16 + l16) * 136 + c * 32 + q * 8];
    f32x4 acc2[4];
#pragma unroll
    for (int u = 0; u < 4; u++) {
        f32x4 z = {0.f, 0.f, 0.f, 0.f};
#pragma unroll
        for (int c = 0; c < 4; c++) {
            bf16x8 wf = *(const bf16x8*)(const void*)&wt2[(u * 16 + l16) * 136 + c * 32 + q * 8];
            z = __builtin_amdgcn_mfma_f32_16x16x32_bf16(a2[c], wf, z, 0, 0, 0);
        }
        acc2[u] = z;
    }

    // ---- fused tail ----
    float lg[4], lbv[4], ng1[4], nb1[4], ng2[4], nb2[4], lw1[4], lw2[4], b2c[4];
#pragma unroll
    for (int u = 0; u < 4; u++) {
        int col = u * 16 + l16;
        b2c[u] = B2[col];
        lg[u] = LG[col]; lbv[u] = LB[col];
        ng1[u] = NG[col]; nb1[u] = NBv[col];
        ng2[u] = NG[64 + col]; nb2[u] = NBv[64 + col];
        lw1[u] = LW[col]; lw2[u] = LW[64 + col];
    }
    float lbias0 = LBias[0];

    float h2[4][4];
    float Sh[4] = {0, 0, 0, 0}, Qh[4] = {0, 0, 0, 0};
#pragma unroll
    for (int u = 0; u < 4; u++)
#pragma unroll
        for (int r = 0; r < 4; r++) {
            float v = acc2[u][r] + b2c[u];
            h2[u][r] = v;
            Sh[r] += v; Qh[r] += v * v;
        }
#pragma unroll
    for (int m = 8; m >= 1; m >>= 1)
#pragma unroll
        for (int r = 0; r < 4; r++) {
            Sh[r] += __shfl_xor(Sh[r], m, 64);
            Qh[r] += __shfl_xor(Qh[r], m, 64);
        }
    float hn[4][4], x1v[4][4];
    float S2[4] = {0, 0, 0, 0}, Q2[4] = {0, 0, 0, 0};
#pragma unroll
    for (int r = 0; r < 4; r++) {
        float mu = Sh[r] * (1.f / 64.f);
        float var = Qh[r] * (1.f / 64.f) - mu * mu;
        float rs = rsqrtf(var + 1e-5f);
        int node = m0 + q * 4 + r;
        int nodeC = node < NN ? node : NN - 1;
#pragma unroll
        for (int u = 0; u < 4; u++) {
            float h = fmaxf((h2[u][r] - mu) * rs * lg[u] + lbv[u], 0.f);
            hn[u][r] = h;
            float xv = X1[(size_t)nodeC * HD + u * 16 + l16];
            x1v[u][r] = xv;
            S2[r] += xv + h;
            Q2[r] += xv * xv + h * h;
        }
    }
#pragma unroll
    for (int m = 8; m >= 1; m >>= 1)
#pragma unroll
        for (int r = 0; r < 4; r++) {
            S2[r] += __shfl_xor(S2[r], m, 64);
            Q2[r] += __shfl_xor(Q2[r], m, 64);
        }
    float contrib[4];
#pragma unroll
    for (int r = 0; r < 4; r++) {
        float mu2 = S2[r] * (1.f / 128.f);
        float var2 = Q2[r] * (1.f / 128.f) - mu2 * mu2;
        float rs2 = rsqrtf(var2 + 1e-5f);
        float c = 0.f;
#pragma unroll
        for (int u = 0; u < 4; u++) {
            float av = fmaxf((x1v[u][r] - mu2) * rs2 * ng1[u] + nb1[u], 0.f);
            float bv = fmaxf((hn[u][r] - mu2) * rs2 * ng2[u] + nb2[u], 0.f);
            c += av * lw1[u] + bv * lw2[u];
        }
        contrib[r] = c;
    }
#pragma unroll
    for (int m = 8; m >= 1; m >>= 1)
#pragma unroll
        for (int r = 0; r < 4; r++) contrib[r] += __shfl_xor(contrib[r], m, 64);
    if (l16 == 0) {
#pragma unroll
        for (int r = 0; r < 4; r++) {
            int node = m0 + q * 4 + r;
            if (node < NN) out[node] = contrib[r] + lbias0;
        }
    }
}

extern "C" void kernel_launch(void* const* d_in, const int* in_sizes, int n_in,
                              void* d_out, int out_size, void* d_ws, size_t ws_size,
                              hipStream_t stream) {
    const float* x = (const float*)d_in[0];
    const int* ei = (const int*)d_in[1];
    const float* encW = (const float*)d_in[2];
    const float* encB = (const float*)d_in[3];
    const float* tptr = (const float*)d_in[4];
    const float* cW1 = (const float*)d_in[5];
    const float* cB1 = (const float*)d_in[6];
    const float* cG1 = (const float*)d_in[7];
    const float* cBE1 = (const float*)d_in[8];
    const float* cW2 = (const float*)d_in[9];
    const float* cB2 = (const float*)d_in[10];
    const float* ln1g = (const float*)d_in[11];
    const float* ln1b = (const float*)d_in[12];
    const float* ng = (const float*)d_in[13];
    const float* nb = (const float*)d_in[14];
    const float* lw = (const float*)d_in[15];
    const float* lb = (const float*)d_in[16];

    char* w = (char*)d_ws;
    size_t off = 0;
    auto carve = [&](size_t bytes) {
        void* p = w + off;
        off += (bytes + 255) & ~(size_t)255;
        return p;
    };
    int* flag = (int*)carve(4);
    int* bcnt = (int*)carve(NBUCK * 4);
    u32* barr = (u32*)carve((size_t)NBUCK * CAP * 4);
    int2* rowdeg = (int2*)carve((size_t)NN * 8);
    u16* eSrc = (u16*)carve((size_t)NBUCK * CAP * 2);
    u16* Abf = (u16*)carve((size_t)NN * HD * 2);
    u16* AGbf = (u16*)carve((size_t)NN * HD * 2);
    float* X1 = (float*)carve((size_t)NN * HD * 4);
    u16* X1bf = (u16*)carve((size_t)NN * HD * 2);

    k_detect<<<1, 256, 0, stream>>>(ei, flag, bcnt);

    const int GB = (NN + 63) / 64;  // 782
    k_bucket_enc<<<NBLK + GB, 256, 0, stream>>>(ei, flag, bcnt, barr, x, encW, encB, Abf);
    k_sort<<<NBUCK, 256, 0, stream>>>(bcnt, barr, eSrc, rowdeg);

    // conv1
    k_agg<<<2048, 256, 0, stream>>>(Abf, rowdeg, eSrc, tptr, AGbf);
    k_mlp<<<GB, 256, 0, stream>>>(AGbf, cW1, cB1, cG1, cBE1, cW2, cB2, X1, X1bf);
    // conv2 (shared weights) + fused tail
    k_agg<<<2048, 256, 0, stream>>>(X1bf, rowdeg, eSrc, tptr, AGbf);
    k_mlpfin<<<GB, 256, 0, stream>>>(AGbf, cW1, cB1, cG1, cBE1, cW2, cB2, X1,
                                     ln1g, ln1b, ng, nb, lw, lb, (float*)d_out);
}

// Round 14
// 216.869 us; speedup vs baseline: 1.0341x; 1.0341x over previous
//
#include <hip/hip_runtime.h>
#include <hip/hip_bf16.h>

// DeeperGCN round-13: best-of consolidation on the R11 champion (220.7us).
// R12's pair-interleave + bf16-self regressed (224us, absmax 0.0176) -> reverted.
// Kept: rowdeg int2 (one metadata load/node). New: k_detect dispatch removed
// (memsetAsync(bcnt) + per-block layout detect in bucket blocks, R8-validated).
// 6 kernel dispatches + 1 tiny memset: bucket+enc -> sort -> agg -> mlp -> agg -> mlpfin.

#define NN 50000
#define EE 800000
#define FIN 128
#define HD 64
#define NBUCK 196       // dst>>8: 196*256 = 50176 >= NN
#define CAP 4608        // bucket capacity: mean 4082 + 8 sigma (validated R8/R10)
#define EPB 2048        // edges per bucket-build block
#define NBLK 391        // 391*2048 = 800768 >= EE

typedef unsigned short u16;
typedef unsigned int u32;
using bf16x8 = __attribute__((ext_vector_type(8))) short;
using f32x4 = __attribute__((ext_vector_type(4))) float;

__device__ __forceinline__ float bf2f(u16 u) {
    u32 x = ((u32)u) << 16;
    float f;
    __builtin_memcpy(&f, &x, 4);
    return f;
}
__device__ __forceinline__ short f2bf(float f) {
    u32 u;
    __builtin_memcpy(&u, &f, 4);
    u32 r = (u + 0x7fffu + ((u >> 16) & 1u)) >> 16;  // RNE
    return (short)r;
}

// ---------------- merged bucket-build + encoder ----------------
// blocks [0, NBLK): bucket 2048 edges each (per-block layout detect).
// blocks [NBLK, NBLK+GB): encoder.
__global__ __launch_bounds__(256) void k_bucket_enc(
    const int* __restrict__ ei, int* __restrict__ bcnt,
    u32* __restrict__ barr, const float* __restrict__ x, const float* __restrict__ W,
    const float* __restrict__ b, u16* __restrict__ Abf) {
    __shared__ short wtE[64 * 136];
    int tid = threadIdx.x;
    if (blockIdx.x < NBLK) {
        __shared__ int hist[NBUCK];
        __shared__ int gbase[NBUCK];
        __shared__ int cur[NBUCK];
        __shared__ int s_is32;
        if (tid == 0) s_is32 = 0;
        for (int i = tid; i < NBUCK; i += 256) { hist[i] = 0; cur[i] = 0; }
        __syncthreads();
        // per-block layout detect: int64 layout => odd words (high halves) all 0
        if (ei[2 * tid + 1] != 0) atomicOr(&s_is32, 1);
        __syncthreads();
        int is32 = s_is32;
        int e0 = blockIdx.x * EPB;
        u32 pk[8];
#pragma unroll
        for (int j = 0; j < 8; j++) {
            int e = e0 + j * 256 + tid;
            if (e < EE) {
                int s, d;
                if (is32) {
                    s = ei[e];
                    d = ei[EE + e];
                } else {
                    int2 sp = ((const int2*)ei)[e];
                    int2 dp = ((const int2*)ei)[EE + e];
                    s = sp.x;
                    d = dp.x;
                }
                pk[j] = (u32)s | ((u32)(d & 255) << 16) | ((u32)(d >> 8) << 24);
                atomicAdd(&hist[d >> 8], 1);
            } else {
                pk[j] = 0xFFFFFFFFu;
            }
        }
        __syncthreads();
        for (int i = tid; i < NBUCK; i += 256)
            if (hist[i] > 0) gbase[i] = atomicAdd(&bcnt[i], hist[i]);
        __syncthreads();
#pragma unroll
        for (int j = 0; j < 8; j++) {
            if (pk[j] != 0xFFFFFFFFu) {
                int bk = pk[j] >> 24;
                int pos = gbase[bk] + atomicAdd(&cur[bk], 1);
                if (pos < CAP) barr[(size_t)bk * CAP + pos] = pk[j] & 0x00FFFFFFu;
            }
        }
        return;
    }
    // encoder: Abf[n,0:64] = bf16(x[n,0:128] @ W + b)
    for (int i = tid; i < FIN * HD; i += 256) wtE[(i & 63) * 136 + (i >> 6)] = f2bf(W[i]);
    __syncthreads();

    int lane = tid & 63, wid = tid >> 6;
    int l16 = lane & 15, q = lane >> 4;
    int m0 = (int)(blockIdx.x - NBLK) * 64 + wid * 16;
    int mrow = m0 + l16;
    if (mrow >= NN) mrow = NN - 1;

    bf16x8 af[4];
#pragma unroll
    for (int c = 0; c < 4; c++) {
        const float4* p = (const float4*)(x + (size_t)mrow * FIN + c * 32 + q * 8);
        float4 p0 = p[0], p1 = p[1];
        af[c][0] = f2bf(p0.x); af[c][1] = f2bf(p0.y); af[c][2] = f2bf(p0.z); af[c][3] = f2bf(p0.w);
        af[c][4] = f2bf(p1.x); af[c][5] = f2bf(p1.y); af[c][6] = f2bf(p1.z); af[c][7] = f2bf(p1.w);
    }
    f32x4 acc[4];
#pragma unroll
    for (int u = 0; u < 4; u++) {
        f32x4 z = {0.f, 0.f, 0.f, 0.f};
#pragma unroll
        for (int c = 0; c < 4; c++) {
            bf16x8 wf = *(const bf16x8*)(const void*)&wtE[(u * 16 + l16) * 136 + c * 32 + q * 8];
            z = __builtin_amdgcn_mfma_f32_16x16x32_bf16(af[c], wf, z, 0, 0, 0);
        }
        acc[u] = z;
    }
#pragma unroll
    for (int u = 0; u < 4; u++) {
        int col = u * 16 + l16;
        float bc = b[col];
#pragma unroll
        for (int r = 0; r < 4; r++) {
            int node = m0 + q * 4 + r;
            if (node < NN) Abf[(size_t)node * HD + col] = (u16)f2bf(acc[u][r] + bc);
        }
    }
}

// ---------------- per-bucket sort: bucket -> sorted CSR runs (dense writes) -------
__global__ __launch_bounds__(256) void k_sort(const int* __restrict__ bcnt,
                                              const u32* __restrict__ barr,
                                              u16* __restrict__ eSrc,
                                              int2* __restrict__ rowdeg) {
    __shared__ u32 pkL[CAP];
    __shared__ u16 outL[CAP];
    __shared__ int hist[256];
    __shared__ int excl[256];
    __shared__ int cur[256];
    int bk = blockIdx.x;
    int t = threadIdx.x;
    int cnt = bcnt[bk];
    if (cnt > CAP) cnt = CAP;
    const u32* bp = barr + (size_t)bk * CAP;
    for (int i = t; i < cnt; i += 256) pkL[i] = bp[i];
    hist[t] = 0;
    __syncthreads();
    for (int i = t; i < cnt; i += 256) atomicAdd(&hist[(pkL[i] >> 16) & 0xFF], 1);
    __syncthreads();
    int v = hist[t];
    excl[t] = v;
    __syncthreads();
#pragma unroll
    for (int d = 1; d < 256; d <<= 1) {
        int u = (t >= d) ? excl[t - d] : 0;
        __syncthreads();
        excl[t] += u;
        __syncthreads();
    }
    int ex = excl[t] - v;
    cur[t] = ex;
    int node = bk * 256 + t;
    if (node < NN) rowdeg[node] = make_int2(bk * CAP + ex, v);
    __syncthreads();
    for (int i = t; i < cnt; i += 256) {
        u32 pk = pkL[i];
        int pos = atomicAdd(&cur[(pk >> 16) & 0xFF], 1);
        outL[pos] = (u16)pk;
    }
    __syncthreads();
    int cnt2 = (cnt + 1) >> 1;
    u32* dst = (u32*)(void*)(eSrc + (size_t)bk * CAP);
    const u32* src = (const u32*)(const void*)outL;
    for (int i = t; i < cnt2; i += 256) dst[i] = src[i];
}

// ---------------- softmax aggregation: 16/8-chunks + 2-in-flight tail (R11) --------
__global__ __launch_bounds__(256) void k_agg(const u16* __restrict__ Xbf,
                                             const float* __restrict__ Xfp,  // self (may be null)
                                             const int2* __restrict__ rowdeg,
                                             const u16* __restrict__ eSrc,
                                             const float* __restrict__ tptr,
                                             u16* __restrict__ OUTbf) {
    int t = threadIdx.x;
    int lane = t & 63, wid = t >> 6;
    int half = lane >> 5, cp = lane & 31;
    float tt = tptr[0];
    for (int n = blockIdx.x * 4 + wid; n < NN; n += gridDim.x * 4) {
        int2 rd = rowdeg[n];
        int s = rd.x, e = rd.x + rd.y;
        float self0, self1;
        if (Xfp) {
            float2 f2 = *(const float2*)(Xfp + (size_t)n * HD + 2 * cp);
            self0 = f2.x; self1 = f2.y;
        } else {
            u32 u = *(const u32*)(const void*)(Xbf + (size_t)n * HD + 2 * cp);
            self0 = bf2f((u16)u); self1 = bf2f((u16)(u >> 16));
        }
        float num0 = 0.f, den0 = 0.f, num1 = 0.f, den1 = 0.f;
        int base = s;
        // 16-edge chunks: 8 gathers in flight per half-wave
        for (; base + 16 <= e; base += 16) {
            int sv[8];
#pragma unroll
            for (int k = 0; k < 8; k++) sv[k] = eSrc[base + 2 * k + half];
            u32 uu[8];
#pragma unroll
            for (int k = 0; k < 8; k++)
                uu[k] = *(const u32*)(const void*)(Xbf + (size_t)sv[k] * HD + 2 * cp);
#pragma unroll
            for (int k = 0; k < 8; k++) {
                float m0 = fmaxf(bf2f((u16)uu[k]), 0.f) + 1e-7f;
                float m1 = fmaxf(bf2f((u16)(uu[k] >> 16)), 0.f) + 1e-7f;
                float p0 = __expf(m0 * tt);
                float p1 = __expf(m1 * tt);
                den0 += p0; num0 += m0 * p0;
                den1 += p1; num1 += m1 * p1;
            }
        }
        // 8-edge chunk
        if (base + 8 <= e) {
            int sv[4];
#pragma unroll
            for (int k = 0; k < 4; k++) sv[k] = eSrc[base + 2 * k + half];
            u32 uu[4];
#pragma unroll
            for (int k = 0; k < 4; k++)
                uu[k] = *(const u32*)(const void*)(Xbf + (size_t)sv[k] * HD + 2 * cp);
#pragma unroll
            for (int k = 0; k < 4; k++) {
                float m0 = fmaxf(bf2f((u16)uu[k]), 0.f) + 1e-7f;
                float m1 = fmaxf(bf2f((u16)(uu[k] >> 16)), 0.f) + 1e-7f;
                float p0 = __expf(m0 * tt);
                float p1 = __expf(m1 * tt);
                den0 += p0; num0 += m0 * p0;
                den1 += p1; num1 += m1 * p1;
            }
            base += 8;
        }
        // paired tail: 2 gathers in flight per half-wave
        int i = base + half;
        for (; i + 2 < e; i += 4) {
            int sva = eSrc[i], svb = eSrc[i + 2];
            u32 ua = *(const u32*)(const void*)(Xbf + (size_t)sva * HD + 2 * cp);
            u32 ub = *(const u32*)(const void*)(Xbf + (size_t)svb * HD + 2 * cp);
            float m0a = fmaxf(bf2f((u16)ua), 0.f) + 1e-7f;
            float m1a = fmaxf(bf2f((u16)(ua >> 16)), 0.f) + 1e-7f;
            float m0b = fmaxf(bf2f((u16)ub), 0.f) + 1e-7f;
            float m1b = fmaxf(bf2f((u16)(ub >> 16)), 0.f) + 1e-7f;
            float p0a = __expf(m0a * tt), p1a = __expf(m1a * tt);
            float p0b = __expf(m0b * tt), p1b = __expf(m1b * tt);
            den0 += p0a + p0b; num0 += m0a * p0a + m0b * p0b;
            den1 += p1a + p1b; num1 += m1a * p1a + m1b * p1b;
        }
        if (i < e) {
            int sv = eSrc[i];
            u32 u = *(const u32*)(const void*)(Xbf + (size_t)sv * HD + 2 * cp);
            float m0 = fmaxf(bf2f((u16)u), 0.f) + 1e-7f;
            float m1 = fmaxf(bf2f((u16)(u >> 16)), 0.f) + 1e-7f;
            float p0 = __expf(m0 * tt);
            float p1 = __expf(m1 * tt);
            den0 += p0; num0 += m0 * p0;
            den1 += p1; num1 += m1 * p1;
        }
        num0 += __shfl_xor(num0, 32, 64);
        den0 += __shfl_xor(den0, 32, 64);
        num1 += __shfl_xor(num1, 32, 64);
        den1 += __shfl_xor(den1, 32, 64);
        if (half == 0) {
            float a0 = num0 / (den0 + 1e-16f) + self0;
            float a1 = num1 / (den1 + 1e-16f) + self1;
            u32 pk = (u32)(u16)f2bf(a0) | ((u32)(u16)f2bf(a1) << 16);
            *(u32*)(void*)(OUTbf + (size_t)n * HD + 2 * cp) = pk;
        }
    }
}

// ---------------- conv1 MLP (MFMA): relu(LN(in@W1+b1))@W2+b2 -> X1 fp32 + bf16 ----------------
__global__ __launch_bounds__(256) void k_mlp(const u16* __restrict__ INbf,
                                             const float* __restrict__ W1,
                                             const float* __restrict__ B1,
                                             const float* __restrict__ G1,
                                             const float* __restrict__ BE1,
                                             const float* __restrict__ W2,
                                             const float* __restrict__ B2,
                                             float* __restrict__ OUTfp,
                                             u16* __restrict__ OUTbf) {
    __shared__ short wt1[128 * 72];
    __shared__ short wt2[64 * 136];
    __shared__ short hbuf[64 * 136];
    int tid = threadIdx.x;
    for (int i = tid; i < HD * 128; i += 256) wt1[(i & 127) * 72 + (i >> 7)] = f2bf(W1[i]);
    for (int i = tid; i < 128 * HD; i += 256) wt2[(i & 63) * 136 + (i >> 6)] = f2bf(W2[i]);
    __syncthreads();

    int lane = tid & 63, wid = tid >> 6;
    int l16 = lane & 15, q = lane >> 4;
    int m0 = blockIdx.x * 64 + wid * 16;
    int mrow = m0 + l16;
    if (mrow >= NN) mrow = NN - 1;

    float b1v[8], g1v[8], bev[8];
#pragma unroll
    for (int tl = 0; tl < 8; tl++) {
        int j = tl * 16 + l16;
        b1v[tl] = B1[j]; g1v[tl] = G1[j]; bev[tl] = BE1[j];
    }

    bf16x8 a0 = *(const bf16x8*)(const void*)(INbf + (size_t)mrow * HD + q * 8);
    bf16x8 a1 = *(const bf16x8*)(const void*)(INbf + (size_t)mrow * HD + 32 + q * 8);
    f32x4 acc1[8];
#pragma unroll
    for (int tl = 0; tl < 8; tl++) {
        bf16x8 w0 = *(const bf16x8*)(const void*)&wt1[(tl * 16 + l16) * 72 + q * 8];
        bf16x8 w1 = *(const bf16x8*)(const void*)&wt1[(tl * 16 + l16) * 72 + 32 + q * 8];
        f32x4 z = {0.f, 0.f, 0.f, 0.f};
        z = __builtin_amdgcn_mfma_f32_16x16x32_bf16(a0, w0, z, 0, 0, 0);
        z = __builtin_amdgcn_mfma_f32_16x16x32_bf16(a1, w1, z, 0, 0, 0);
        acc1[tl] = z;
    }
    float S[4] = {0, 0, 0, 0}, Q[4] = {0, 0, 0, 0};
#pragma unroll
    for (int tl = 0; tl < 8; tl++)
#pragma unroll
        for (int r = 0; r < 4; r++) {
            float v = acc1[tl][r] + b1v[tl];
            acc1[tl][r] = v;
            S[r] += v; Q[r] += v * v;
        }
#pragma unroll
    for (int m = 8; m >= 1; m >>= 1)
#pragma unroll
        for (int r = 0; r < 4; r++) {
            S[r] += __shfl_xor(S[r], m, 64);
            Q[r] += __shfl_xor(Q[r], m, 64);
        }
    float mu[4], rs[4];
#pragma unroll
    for (int r = 0; r < 4; r++) {
        mu[r] = S[r] * (1.f / 128.f);
        float var = Q[r] * (1.f / 128.f) - mu[r] * mu[r];
        rs[r] = rsqrtf(var + 1e-5f);
    }
#pragma unroll
    for (int tl = 0; tl < 8; tl++)
#pragma unroll
        for (int r = 0; r < 4; r++) {
            float h = fmaxf((acc1[tl][r] - mu[r]) * rs[r] * g1v[tl] + bev[tl], 0.f);
            hbuf[(wid * 16 + q * 4 + r) * 136 + tl * 16 + l16] = f2bf(h);
        }
    // wave-private LDS rows; per-wave DS ordering suffices

    bf16x8 a2[4];
#pragma unroll
    for (int c = 0; c < 4; c++)
        a2[c] = *(const bf16x8*)(const void*)&hbuf[(wid * 16 + l16) * 136 + c * 32 + q * 8];
    f32x4 acc2[4];
#pragma unroll
    for (int u = 0; u < 4; u++) {
        f32x4 z = {0.f, 0.f, 0.f, 0.f};
#pragma unroll
        for (int c = 0; c < 4; c++) {
            bf16x8 wf = *(const bf16x8*)(const void*)&wt2[(u * 16 + l16) * 136 + c * 32 + q * 8];
            z = __builtin_amdgcn_mfma_f32_16x16x32_bf16(a2[c], wf, z, 0, 0, 0);
        }
        acc2[u] = z;
    }
#pragma unroll
    for (int u = 0; u < 4; u++) {
        int col = u * 16 + l16;
        float bc = B2[col];
#pragma unroll
        for (int r = 0; r < 4; r++) {
            int node = m0 + q * 4 + r;
            if (node < NN) {
                float val = acc2[u][r] + bc;
                OUTfp[(size_t)node * HD + col] = val;
                OUTbf[(size_t)node * HD + col] = (u16)f2bf(val);
            }
        }
    }
}

// ---------------- conv2 MLP + fused tail ----------------
__global__ __launch_bounds__(256) void k_mlpfin(const u16* __restrict__ INbf,
                                                const float* __restrict__ W1,
                                                const float* __restrict__ B1,
                                                const float* __restrict__ G1,
                                                const float* __restrict__ BE1,
                                                const float* __restrict__ W2,
                                                const float* __restrict__ B2,
                                                const float* __restrict__ X1,
                                                const float* __restrict__ LG,
                                                const float* __restrict__ LB,
                                                const float* __restrict__ NG,
                                                const float* __restrict__ NBv,
                                                const float* __restrict__ LW,
                                                const float* __restrict__ LBias,
                                                float* __restrict__ out) {
    __shared__ short wt1[128 * 72];
    __shared__ short wt2[64 * 136];
    __shared__ short hbuf[64 * 136];
    int tid = threadIdx.x;
    for (int i = tid; i < HD * 128; i += 256) wt1[(i & 127) * 72 + (i >> 7)] = f2bf(W1[i]);
    for (int i = tid; i < 128 * HD; i += 256) wt2[(i & 63) * 136 + (i >> 6)] = f2bf(W2[i]);
    __syncthreads();

    int lane = tid & 63, wid = tid >> 6;
    int l16 = lane & 15, q = lane >> 4;
    int m0 = blockIdx.x * 64 + wid * 16;
    int mrow = m0 + l16;
    if (mrow >= NN) mrow = NN - 1;

    float b1v[8], g1v[8], bev[8];
#pragma unroll
    for (int tl = 0; tl < 8; tl++) {
        int j = tl * 16 + l16;
        b1v[tl] = B1[j]; g1v[tl] = G1[j]; bev[tl] = BE1[j];
    }

    bf16x8 a0 = *(const bf16x8*)(const void*)(INbf + (size_t)mrow * HD + q * 8);
    bf16x8 a1 = *(const bf16x8*)(const void*)(INbf + (size_t)mrow * HD + 32 + q * 8);
    f32x4 acc1[8];
#pragma unroll
    for (int tl = 0; tl < 8; tl++) {
        bf16x8 w0 = *(const bf16x8*)(const void*)&wt1[(tl * 16 + l16) * 72 + q * 8];
        bf16x8 w1 = *(const bf16x8*)(const void*)&wt1[(tl * 16 + l16) * 72 + 32 + q * 8];
        f32x4 z = {0.f, 0.f, 0.f, 0.f};
        z = __builtin_amdgcn_mfma_f32_16x16x32_bf16(a0, w0, z, 0, 0, 0);
        z = __builtin_amdgcn_mfma_f32_16x16x32_bf16(a1, w1, z, 0, 0, 0);
        acc1[tl] = z;
    }
    float S[4] = {0, 0, 0, 0}, Q[4] = {0, 0, 0, 0};
#pragma unroll
    for (int tl = 0; tl < 8; tl++)
#pragma unroll
        for (int r = 0; r < 4; r++) {
            float v = acc1[tl][r] + b1v[tl];
            acc1[tl][r] = v;
            S[r] += v; Q[r] += v * v;
        }
#pragma unroll
    for (int m = 8; m >= 1; m >>= 1)
#pragma unroll
        for (int r = 0; r < 4; r++) {
            S[r] += __shfl_xor(S[r], m, 64);
            Q[r] += __shfl_xor(Q[r], m, 64);
        }
#pragma unroll
    for (int r = 0; r < 4; r++) {
        float mu = S[r] * (1.f / 128.f);
        float var = Q[r] * (1.f / 128.f) - mu * mu;
        float rs = rsqrtf(var + 1e-5f);
        S[r] = mu; Q[r] = rs;  // reuse
    }
#pragma unroll
    for (int tl = 0; tl < 8; tl++)
#pragma unroll
        for (int r = 0; r < 4; r++) {
            float h = fmaxf((acc1[tl][r] - S[r]) * Q[r] * g1v[tl] + bev[tl], 0.f);
            hbuf[(wid * 16 + q * 4 + r) * 136 + tl * 16 + l16] = f2bf(h);
        }

    bf16x8 a2[4];
#pragma unroll
    for (int c = 0; c < 4; c++)
        a2[c] = *(const bf16x8*)(const void*)&hbuf[(wid * 16 + l16) * 136 + c * 32 + q * 8];
    f32x4 acc2[4];
#pragma unroll
    for (int u = 0; u < 4; u++) {
        f32x4 z = {0.f, 0.f, 0.f, 0.f};
#pragma unroll
        for (int c = 0; c < 4; c++) {
            bf16x8 wf = *(const bf16x8*)(const void*)&wt2[(u * 16 + l16) * 136 + c * 32 + q * 8];
            z = __builtin_amdgcn_mfma_f32_16x16x32_bf16(a2[c], wf, z, 0, 0, 0);
        }
        acc2[u] = z;
    }

    // ---- fused tail ----
    float lg[4], lbv[4], ng1[4], nb1[4], ng2[4], nb2[4], lw1[4], lw2[4], b2c[4];
#pragma unroll
    for (int u = 0; u < 4; u++) {
        int col = u * 16 + l16;
        b2c[u] = B2[col];
        lg[u] = LG[col]; lbv[u] = LB[col];
        ng1[u] = NG[col]; nb1[u] = NBv[col];
        ng2[u] = NG[64 + col]; nb2[u] = NBv[64 + col];
        lw1[u] = LW[col]; lw2[u] = LW[64 + col];
    }
    float lbias0 = LBias[0];

    float h2[4][4];
    float Sh[4] = {0, 0, 0, 0}, Qh[4] = {0, 0, 0, 0};
#pragma unroll
    for (int u = 0; u < 4; u++)
#pragma unroll
        for (int r = 0; r < 4; r++) {
            float v = acc2[u][r] + b2c[u];
            h2[u][r] = v;
            Sh[r] += v; Qh[r] += v * v;
        }
#pragma unroll
    for (int m = 8; m >= 1; m >>= 1)
#pragma unroll
        for (int r = 0; r < 4; r++) {
            Sh[r] += __shfl_xor(Sh[r], m, 64);
            Qh[r] += __shfl_xor(Qh[r], m, 64);
        }
    float hn[4][4], x1v[4][4];
    float S2[4] = {0, 0, 0, 0}, Q2[4] = {0, 0, 0, 0};
#pragma unroll
    for (int r = 0; r < 4; r++) {
        float mu = Sh[r] * (1.f / 64.f);
        float var = Qh[r] * (1.f / 64.f) - mu * mu;
        float rs = rsqrtf(var + 1e-5f);
        int node = m0 + q * 4 + r;
        int nodeC = node < NN ? node : NN - 1;
#pragma unroll
        for (int u = 0; u < 4; u++) {
            float h = fmaxf((h2[u][r] - mu) * rs * lg[u] + lbv[u], 0.f);
            hn[u][r] = h;
            float xv = X1[(size_t)nodeC * HD + u * 16 + l16];
            x1v[u][r] = xv;
            S2[r] += xv + h;
            Q2[r] += xv * xv + h * h;
        }
    }
#pragma unroll
    for (int m = 8; m >= 1; m >>= 1)
#pragma unroll
        for (int r = 0; r < 4; r++) {
            S2[r] += __shfl_xor(S2[r], m, 64);
            Q2[r] += __shfl_xor(Q2[r], m, 64);
        }
    float contrib[4];
#pragma unroll
    for (int r = 0; r < 4; r++) {
        float mu2 = S2[r] * (1.f / 128.f);
        float var2 = Q2[r] * (1.f / 128.f) - mu2 * mu2;
        float rs2 = rsqrtf(var2 + 1e-5f);
        float c = 0.f;
#pragma unroll
        for (int u = 0; u < 4; u++) {
            float av = fmaxf((x1v[u][r] - mu2) * rs2 * ng1[u] + nb1[u], 0.f);
            float bv = fmaxf((hn[u][r] - mu2) * rs2 * ng2[u] + nb2[u], 0.f);
            c += av * lw1[u] + bv * lw2[u];
        }
        contrib[r] = c;
    }
#pragma unroll
    for (int m = 8; m >= 1; m >>= 1)
#pragma unroll
        for (int r = 0; r < 4; r++) contrib[r] += __shfl_xor(contrib[r], m, 64);
    if (l16 == 0) {
#pragma unroll
        for (int r = 0; r < 4; r++) {
            int node = m0 + q * 4 + r;
            if (node < NN) out[node] = contrib[r] + lbias0;
        }
    }
}

extern "C" void kernel_launch(void* const* d_in, const int* in_sizes, int n_in,
                              void* d_out, int out_size, void* d_ws, size_t ws_size,
                              hipStream_t stream) {
    const float* x = (const float*)d_in[0];
    const int* ei = (const int*)d_in[1];
    const float* encW = (const float*)d_in[2];
    const float* encB = (const float*)d_in[3];
    const float* tptr = (const float*)d_in[4];
    const float* cW1 = (const float*)d_in[5];
    const float* cB1 = (const float*)d_in[6];
    const float* cG1 = (const float*)d_in[7];
    const float* cBE1 = (const float*)d_in[8];
    const float* cW2 = (const float*)d_in[9];
    const float* cB2 = (const float*)d_in[10];
    const float* ln1g = (const float*)d_in[11];
    const float* ln1b = (const float*)d_in[12];
    const float* ng = (const float*)d_in[13];
    const float* nb = (const float*)d_in[14];
    const float* lw = (const float*)d_in[15];
    const float* lb = (const float*)d_in[16];

    char* w = (char*)d_ws;
    size_t off = 0;
    auto carve = [&](size_t bytes) {
        void* p = w + off;
        off += (bytes + 255) & ~(size_t)255;
        return p;
    };
    int* bcnt = (int*)carve(NBUCK * 4);
    u32* barr = (u32*)carve((size_t)NBUCK * CAP * 4);
    int2* rowdeg = (int2*)carve((size_t)NN * 8);
    u16* eSrc = (u16*)carve((size_t)NBUCK * CAP * 2);
    u16* Abf = (u16*)carve((size_t)NN * HD * 2);
    u16* AGbf = (u16*)carve((size_t)NN * HD * 2);
    float* X1 = (float*)carve((size_t)NN * HD * 4);
    u16* X1bf = (u16*)carve((size_t)NN * HD * 2);

    hipMemsetAsync(bcnt, 0, NBUCK * 4, stream);

    const int GB = (NN + 63) / 64;  // 782
    k_bucket_enc<<<NBLK + GB, 256, 0, stream>>>(ei, bcnt, barr, x, encW, encB, Abf);
    k_sort<<<NBUCK, 256, 0, stream>>>(bcnt, barr, eSrc, rowdeg);

    // conv1
    k_agg<<<2048, 256, 0, stream>>>(Abf, nullptr, rowdeg, eSrc, tptr, AGbf);
    k_mlp<<<GB, 256, 0, stream>>>(AGbf, cW1, cB1, cG1, cBE1, cW2, cB2, X1, X1bf);
    // conv2 (shared weights) + fused tail
    k_agg<<<2048, 256, 0, stream>>>(X1bf, X1, rowdeg, eSrc, tptr, AGbf);
    k_mlpfin<<<GB, 256, 0, stream>>>(AGbf, cW1, cB1, cG1, cBE1, cW2, cB2, X1,
                                     ln1g, ln1b, ng, nb, lw, lb, (float*)d_out);
}